// Round 6
// baseline (22.611 us; speedup 1.0000x reference)
//
#include <hip/hip_runtime.h>

// BackprojectDepth: out[b, 0:3, k] = depth[b, idx] * (inv_K[b,:3,:3] @ [gx, gy, 1])
//                   out[b, 3, k]   = 1.0
// idx = top_k_indices[b,k], gx = idx % W, gy = idx / W.
// pix_coords input is a meshgrid -> recomputed arithmetically, never read.
//
// Round 6: R3 config (best: 18.3us; 2048 blocks, ILP=4, XCD remap, nt idx/stores)
// + ONE change: depth gathers bypass L1 via inline-asm `global_load_dword ... sc0`
// (L2-cached, no L1 allocation). Random gather into 1.9MB/batch has ~2% L1 hit
// rate, but every miss still allocates/tracks through the per-CU L1 path
// (~256 line transactions per wave). sc0 relieves that path.

#define BB 16
#define HH 384
#define WW 1280
#define HWSZ (HH * WW)
#define KK 131072
#define NXCD 8
#define BLOCKS_PER_BATCH (KK / (256 * 4))    // 128
#define TOTAL_BLOCKS (BB * BLOCKS_PER_BATCH) // 2048

typedef float v4f __attribute__((ext_vector_type(4)));
typedef int   v4i __attribute__((ext_vector_type(4)));

__global__ __launch_bounds__(256) void backproject_kernel(
    const float* __restrict__ depth,   // B*HW
    const float* __restrict__ invK,    // B*16
    const int*   __restrict__ topk,    // B*K
    float*       __restrict__ out)     // B*4*K
{
    // Phys block i -> XCD i%8. Give XCD x a contiguous logical range -> XCD x
    // serves batches 2x,2x+1 only (depth working set 3.75MB fits its 4MB L2).
    const int xcd  = blockIdx.x & (NXCD - 1);
    const int slot = blockIdx.x >> 3;                       // 0..255
    const int logical = xcd * (TOTAL_BLOCKS / NXCD) + slot; // 0..2047
    const int b   = logical >> 7;                           // /128 -> batch
    const int blk = logical & 127;                          // block within batch
    const int k0  = blk * 1024 + threadIdx.x * 4;

    // 3x3 of inv_K for this batch (uniform address -> scalar broadcast)
    const float* __restrict__ M = invK + b * 16;
    const float m00 = M[0], m01 = M[1], m02 = M[2];
    const float m10 = M[4], m11 = M[5], m12 = M[6];
    const float m20 = M[8], m21 = M[9], m22 = M[10];

    const v4i idx4 = __builtin_nontemporal_load(
        reinterpret_cast<const v4i*>(topk + b * KK + k0));
    const float* __restrict__ db = depth + b * HWSZ;

    const int i0 = idx4[0], i1 = idx4[1], i2 = idx4[2], i3 = idx4[3];

    // 4 independent gathers, L1-bypass (sc0), one waitcnt for all.
    float d0, d1, d2, d3;
    {
        const float* a0 = db + i0;
        const float* a1 = db + i1;
        const float* a2 = db + i2;
        const float* a3 = db + i3;
        asm volatile(
            "global_load_dword %0, %4, off sc0\n\t"
            "global_load_dword %1, %5, off sc0\n\t"
            "global_load_dword %2, %6, off sc0\n\t"
            "global_load_dword %3, %7, off sc0\n\t"
            "s_waitcnt vmcnt(0)"
            : "=&v"(d0), "=&v"(d1), "=&v"(d2), "=&v"(d3)
            : "v"(a0), "v"(a1), "v"(a2), "v"(a3));
    }

    const int idxs[4] = {i0, i1, i2, i3};
    const float dd[4] = {d0, d1, d2, d3};
    float ox[4], oy[4], oz[4];
#pragma unroll
    for (int j = 0; j < 4; ++j) {
        const int idx = idxs[j];
        const float gx = (float)(idx % WW);
        const float gy = (float)(idx / WW);
        ox[j] = dd[j] * fmaf(m00, gx, fmaf(m01, gy, m02));
        oy[j] = dd[j] * fmaf(m10, gx, fmaf(m11, gy, m12));
        oz[j] = dd[j] * fmaf(m20, gx, fmaf(m21, gy, m22));
    }

    float* __restrict__ ob = out + (size_t)b * 4 * KK + k0;
    v4f vx = {ox[0], ox[1], ox[2], ox[3]};
    v4f vy = {oy[0], oy[1], oy[2], oy[3]};
    v4f vz = {oz[0], oz[1], oz[2], oz[3]};
    v4f vw = {1.f, 1.f, 1.f, 1.f};
    __builtin_nontemporal_store(vx, reinterpret_cast<v4f*>(ob + 0 * KK));
    __builtin_nontemporal_store(vy, reinterpret_cast<v4f*>(ob + 1 * KK));
    __builtin_nontemporal_store(vz, reinterpret_cast<v4f*>(ob + 2 * KK));
    __builtin_nontemporal_store(vw, reinterpret_cast<v4f*>(ob + 3 * KK));
}

extern "C" void kernel_launch(void* const* d_in, const int* in_sizes, int n_in,
                              void* d_out, int out_size, void* d_ws, size_t ws_size,
                              hipStream_t stream) {
    const float* depth = (const float*)d_in[0];     // (B,1,H,W) f32
    const float* invK  = (const float*)d_in[1];     // (B,4,4) f32
    // d_in[2] = pix_coords — intentionally unused (recomputed from index)
    const int*   topk  = (const int*)d_in[3];       // (B,K) i32
    float* out = (float*)d_out;                     // (B,4,K) f32

    backproject_kernel<<<TOTAL_BLOCKS, 256, 0, stream>>>(depth, invK, topk, out);
}

// Round 7
// 22.579 us; speedup vs baseline: 1.0014x; 1.0014x over previous
//
#include <hip/hip_runtime.h>

// BackprojectDepth: out[b, 0:3, k] = depth[b, idx] * (inv_K[b,:3,:3] @ [gx, gy, 1])
//                   out[b, 3, k]   = 1.0
// idx = top_k_indices[b,k], gx = idx % W, gy = idx / W.
// pix_coords input is a meshgrid -> recomputed arithmetically, never read.
//
// Round 7: two-phase. Kernel 1 warms each XCD's L2 with its 2 batches of depth
// (coalesced reads, 3.75MB/XCD < 4MB L2) and writes the constant w=1 channel.
// Kernel 2 = R3 best structure (2048 blocks, ILP=4, XCD remap, nt idx load,
// nt stores, plain gathers) minus the w store. Dispatch ordering guarantees
// warm-before-gather; L2 persists across dispatch boundaries (only L1/vector
// cache is invalidated). R6 lesson: sc0 kills L2 caching -> plain gathers.

#define BB 16
#define HH 384
#define WW 1280
#define HWSZ (HH * WW)           // 491520
#define HW4 (HWSZ / 4)           // 122880 float4 per batch
#define KK 131072
#define NXCD 8
#define BLOCKS_PER_BATCH (KK / (256 * 4))    // 128
#define TOTAL_BLOCKS (BB * BLOCKS_PER_BATCH) // 2048
#define WARM_F4_PER_BLOCK (HW4 / BLOCKS_PER_BATCH) // 960

typedef float v4f __attribute__((ext_vector_type(4)));
typedef int   v4i __attribute__((ext_vector_type(4)));

__device__ __forceinline__ void xcd_map(int bid, int& b, int& blk) {
    const int xcd  = bid & (NXCD - 1);
    const int slot = bid >> 3;                              // 0..255
    const int logical = xcd * (TOTAL_BLOCKS / NXCD) + slot; // 0..2047
    b   = logical >> 7;   // batch (2 per XCD)
    blk = logical & 127;  // block within batch
}

// Kernel 1: warm L2 with depth (coalesced) + write w=1 channel.
__global__ __launch_bounds__(256) void warm_kernel(
    const float* __restrict__ depth, float* __restrict__ out)
{
    int b, blk;
    xcd_map(blockIdx.x, b, blk);

    const v4f* __restrict__ d4 = reinterpret_cast<const v4f*>(depth) + b * HW4;
    float acc = 0.f;
#pragma unroll
    for (int it = 0; it < 4; ++it) {
        const int i = blk * WARM_F4_PER_BLOCK + it * 256 + threadIdx.x;
        if (it < 3 || i < (blk + 1) * WARM_F4_PER_BLOCK) {
            const v4f v = d4[i];
            acc += v[0] + v[1] + v[2] + v[3];
        }
    }
    asm volatile("" :: "v"(acc));   // keep warm loads live, no output

    const int k0 = blk * 1024 + threadIdx.x * 4;
    float* __restrict__ ob = out + (size_t)b * 4 * KK + 3 * KK + k0;
    v4f vw = {1.f, 1.f, 1.f, 1.f};
    __builtin_nontemporal_store(vw, reinterpret_cast<v4f*>(ob));
}

// Kernel 2: gather + project, channels 0..2 only (R3 structure).
__global__ __launch_bounds__(256) void backproject_kernel(
    const float* __restrict__ depth,   // B*HW
    const float* __restrict__ invK,    // B*16
    const int*   __restrict__ topk,    // B*K
    float*       __restrict__ out)     // B*4*K
{
    int b, blk;
    xcd_map(blockIdx.x, b, blk);
    const int k0 = blk * 1024 + threadIdx.x * 4;

    const float* __restrict__ M = invK + b * 16;
    const float m00 = M[0], m01 = M[1], m02 = M[2];
    const float m10 = M[4], m11 = M[5], m12 = M[6];
    const float m20 = M[8], m21 = M[9], m22 = M[10];

    const v4i idx4 = __builtin_nontemporal_load(
        reinterpret_cast<const v4i*>(topk + b * KK + k0));
    const float* __restrict__ db = depth + b * HWSZ;

    const int idxs[4] = {idx4[0], idx4[1], idx4[2], idx4[3]};
    float d[4];
#pragma unroll
    for (int j = 0; j < 4; ++j) d[j] = db[idxs[j]];   // plain loads: L1+L2 cached

    float ox[4], oy[4], oz[4];
#pragma unroll
    for (int j = 0; j < 4; ++j) {
        const int idx = idxs[j];
        const float gx = (float)(idx % WW);
        const float gy = (float)(idx / WW);
        ox[j] = d[j] * fmaf(m00, gx, fmaf(m01, gy, m02));
        oy[j] = d[j] * fmaf(m10, gx, fmaf(m11, gy, m12));
        oz[j] = d[j] * fmaf(m20, gx, fmaf(m21, gy, m22));
    }

    float* __restrict__ ob = out + (size_t)b * 4 * KK + k0;
    v4f vx = {ox[0], ox[1], ox[2], ox[3]};
    v4f vy = {oy[0], oy[1], oy[2], oy[3]};
    v4f vz = {oz[0], oz[1], oz[2], oz[3]};
    __builtin_nontemporal_store(vx, reinterpret_cast<v4f*>(ob + 0 * KK));
    __builtin_nontemporal_store(vy, reinterpret_cast<v4f*>(ob + 1 * KK));
    __builtin_nontemporal_store(vz, reinterpret_cast<v4f*>(ob + 2 * KK));
}

extern "C" void kernel_launch(void* const* d_in, const int* in_sizes, int n_in,
                              void* d_out, int out_size, void* d_ws, size_t ws_size,
                              hipStream_t stream) {
    const float* depth = (const float*)d_in[0];     // (B,1,H,W) f32
    const float* invK  = (const float*)d_in[1];     // (B,4,4) f32
    // d_in[2] = pix_coords — intentionally unused (recomputed from index)
    const int*   topk  = (const int*)d_in[3];       // (B,K) i32
    float* out = (float*)d_out;                     // (B,4,K) f32

    warm_kernel<<<TOTAL_BLOCKS, 256, 0, stream>>>(depth, out);
    backproject_kernel<<<TOTAL_BLOCKS, 256, 0, stream>>>(depth, invK, topk, out);
}